// Round 13
// baseline (135.218 us; speedup 1.0000x reference)
//
#include <hip/hip_runtime.h>
#include <hip/hip_bf16.h>
#include <math.h>

#define B_  512
#define I_  8
#define C_  1152
#define J_  10
#define S_  16
#define K1  9216
#define NKB 288     // sgemm K-blocks (K=9216/32)
#define KBT 16      // tgemm K-blocks (K=512/32)

typedef short short8 __attribute__((ext_vector_type(8)));
typedef float floatx4 __attribute__((ext_vector_type(4)));

__device__ inline unsigned short f2bf(float f) {
    unsigned int u = __float_as_uint(f);
    return (unsigned short)((u + 0x7FFFu + ((u >> 16) & 1u)) >> 16);
}
// HW packed f32->bf16 RNE (v_cvt_pk_bf16_f32 on gfx950): low16 = a, high16 = b
__device__ inline unsigned int pack2(float a, float b) {
    __hip_bfloat162 h = __float22bfloat162_rn(float2{a, b});
    return *reinterpret_cast<unsigned int*>(&h);
}

// ---------------------------------------------------------------------------
// PACK: 721 blocks x 512 threads (reads x once; zeroes b_ij).
__global__ __launch_bounds__(512) void k_pack(const float* __restrict__ x,
                                              const float* __restrict__ W,
                                              uint4* __restrict__ Bs,
                                              uint4* __restrict__ Bt,
                                              uint4* __restrict__ Wf,
                                              unsigned short* __restrict__ W2,
                                              float* __restrict__ b_ij) {
    __shared__ float lds[10240];
    const int task = blockIdx.x;
    const int t = threadIdx.x;
    const int w = t >> 6, L = t & 63, quad = L >> 4;

    if (task < 576) {                       // ---- x tile -> Bs + Bt
        const int bt = task / 36, kt = task % 36;
        const int b0 = bt * 32, k0 = kt * 256;
        #pragma unroll
        for (int p = 0; p < 4; p++) {
            int f4 = p * 512 + t;
            int row = f4 >> 6, c4 = (f4 & 63) << 2;
            *(float4*)&lds[row * 260 + c4] =
                *(const float4*)&x[(size_t)(b0 + row) * K1 + k0 + c4];
        }
        __syncthreads();
        #pragma unroll
        for (int p = 0; p < 2; p++) {
            const int bl = p * 16 + (L & 15);
            const float* s = &lds[bl * 260 + w * 32 + quad * 8];
            uint4 o;
            o.x = pack2(s[0], s[1]); o.y = pack2(s[2], s[3]);
            o.z = pack2(s[4], s[5]); o.w = pack2(s[6], s[7]);
            Bs[((size_t)(bt * 2 + p) * NKB + kt * 8 + w) * 64 + L] = o;
        }
        #pragma unroll
        for (int p = 0; p < 2; p++) {
            const int ntl = w * 2 + p;
            const int nl = ntl * 16 + (L & 15);
            float v[8];
            #pragma unroll
            for (int e = 0; e < 8; e++) v[e] = lds[(quad * 8 + e) * 260 + nl];
            uint4 o;
            o.x = pack2(v[0], v[1]); o.y = pack2(v[2], v[3]);
            o.z = pack2(v[4], v[5]); o.w = pack2(v[6], v[7]);
            Bt[((size_t)(kt * 16 + ntl) * KBT + bt) * 64 + L] = o;
        }
    } else if (task < 720) {                // ---- W chunk -> Wf + W2
        const int c0 = (task - 576) * 8;
        #pragma unroll
        for (int p = 0; p < 5; p++) {
            int f4 = p * 512 + t;
            int cc = f4 / 320, off4 = (f4 % 320) << 2;
            *(float4*)&lds[cc * 1280 + off4] =
                *(const float4*)&W[(size_t)(c0 + cc) * 1280 + off4];
        }
        __syncthreads();
        #pragma unroll
        for (int p = 0; p < 3; p++) {
            int o = p * 512 + t;
            if (o < 1280) {
                int j = o >> 7, i = (o >> 4) & 7, m = o & 15;
                int k0w = i * C_ + c0;
                int Lw = m | (((k0w >> 3) & 3) << 4);
                float v[8];
                #pragma unroll
                for (int e = 0; e < 8; e++)
                    v[e] = lds[e * 1280 + j * 128 + m * 8 + i];
                uint4 og;
                og.x = pack2(v[0], v[1]); og.y = pack2(v[2], v[3]);
                og.z = pack2(v[4], v[5]); og.w = pack2(v[6], v[7]);
                Wf[((size_t)j * NKB + (k0w >> 5)) * 64 + Lw] = og;
            }
        }
        #pragma unroll
        for (int p = 0; p < 2; p++) {
            int o = p * 512 + t;
            if (o < 640) {
                int j = o >> 6, i = (o >> 3) & 7, cc = o & 7;
                unsigned int r8[8];
                #pragma unroll
                for (int h = 0; h < 8; h++)
                    r8[h] = pack2(lds[cc * 1280 + j * 128 + (2 * h) * 8 + i],
                                  lds[cc * 1280 + j * 128 + (2 * h + 1) * 8 + i]);
                unsigned short* dst = W2 + ((size_t)(j * 8 + i) * C_ + c0 + cc) * 16;
                *(uint4*)dst       = make_uint4(r8[0], r8[1], r8[2], r8[3]);
                *(uint4*)(dst + 8) = make_uint4(r8[4], r8[5], r8[6], r8[7]);
            }
        }
    } else {                                // ---- zero b_ij
        for (int idx = t; idx < C_ * J_; idx += 512) b_ij[idx] = 0.0f;
    }
}

// ---------------------------------------------------------------------------
// SGEMM + fused fold + reduce + squash.
// grid (32 nt, 10 j) = 320 blocks x 512 thr (8 waves = 8-way K-split).
// ILP-2 MFMA accumulators (even/odd k) halve the dependent-MFMA chain.
// Fold: hi-unpack skips the 0xffff0000 mask (<=2^-7 pre-RNE perturbation,
// statistically sub-ulp after re-round; threshold headroom 4x).
// mode 0: uniform cnorm=0.1; mode 1: softmax fold -> Vf; mode 2: fold -> out.
__global__ __launch_bounds__(512) void k_sgemm_f(const short8* __restrict__ Wf,
                                                 const short8* __restrict__ Bs,
                                                 const float* __restrict__ b_ij,
                                                 unsigned short* __restrict__ Vf,
                                                 float* __restrict__ out,
                                                 int mode) {
    __shared__ float smf[1152 + 2048];   // cn[1152] + parts[8 waves][256]
    const int t = threadIdx.x, w = t >> 6, L = t & 63, quad = L >> 4;
    const int j  = blockIdx.y;
    const int nt = blockIdx.x;           // 16-b tile, 0..31

    if (mode) {
        for (int c = t; c < C_; c += 512) {
            float bv[J_], mx = -1e30f;
            #pragma unroll
            for (int jj = 0; jj < J_; jj++) {
                bv[jj] = b_ij[c * J_ + jj]; mx = fmaxf(mx, bv[jj]);
            }
            float sum = 0.0f;
            #pragma unroll
            for (int jj = 0; jj < J_; jj++) sum += __expf(bv[jj] - mx);
            smf[c] = __expf(bv[j] - mx) / sum;
        }
    }
    __syncthreads();

    const short8* pA = Wf + ((size_t)j * NKB + w * 36) * 64 + L;
    const short8* pB = Bs + ((size_t)nt * NKB + w * 36) * 64 + L;
    floatx4 acc0 = {0.f, 0.f, 0.f, 0.f}, acc1 = acc0;
    if (mode) {
        #pragma unroll 3
        for (int i = 0; i < 36; i += 2) {
            #pragma unroll
            for (int q = 0; q < 2; q++) {
                short8 a = pA[(i + q) * 64];
                const int cb = (i + q) * 32 + quad * 8;   // (w*36*32) % 1152 == 0
                float4 cl = *(const float4*)&smf[cb];
                float4 ch = *(const float4*)&smf[cb + 4];
                float cn8[8] = {cl.x, cl.y, cl.z, cl.w, ch.x, ch.y, ch.z, ch.w};
                unsigned int* au = (unsigned int*)&a;
                short8 a2; unsigned int* ao = (unsigned int*)&a2;
                #pragma unroll
                for (int h = 0; h < 4; h++) {
                    float f0 = __uint_as_float(au[h] << 16) * cn8[2 * h];
                    // no mask: hi bf16 + garbage low mantissa bits (<2^-7 rel)
                    float f1 = __uint_as_float(au[h])       * cn8[2 * h + 1];
                    ao[h] = pack2(f0, f1);
                }
                if (q == 0)
                    acc0 = __builtin_amdgcn_mfma_f32_16x16x32_bf16(a2, pB[(i + q) * 64], acc0, 0, 0, 0);
                else
                    acc1 = __builtin_amdgcn_mfma_f32_16x16x32_bf16(a2, pB[(i + q) * 64], acc1, 0, 0, 0);
            }
        }
    } else {
        #pragma unroll 3
        for (int i = 0; i < 36; i += 2) {
            acc0 = __builtin_amdgcn_mfma_f32_16x16x32_bf16(pA[i * 64], pB[i * 64], acc0, 0, 0, 0);
            acc1 = __builtin_amdgcn_mfma_f32_16x16x32_bf16(pA[(i + 1) * 64], pB[(i + 1) * 64], acc1, 0, 0, 0);
        }
    }
    floatx4 acc = acc0 + acc1;

    const int col = L & 15, rw = quad << 2;
    float* base = &smf[1152 + w * 256];
    #pragma unroll
    for (int r = 0; r < 4; r++)
        base[(rw + r) * 16 + col] = acc[r];
    __syncthreads();

    if (t < 16) {                        // reduce 8 partials + squash (bl = t)
        float sv[S_]; float msq = 0.f;
        #pragma unroll
        for (int s = 0; s < S_; s++) {
            float a = 0.f;
            #pragma unroll
            for (int w8 = 0; w8 < 8; w8++)
                a += smf[1152 + w8 * 256 + s * 16 + t];
            if (mode == 0) a *= 0.1f;
            sv[s] = a; msq += a * a;
        }
        const float scale = msq / ((1.f + msq) * sqrtf(msq));
        const int b = nt * 16 + t;       // global b (0..511)
        if (mode < 2) {
            const int kb = b >> 5, lh = (b >> 3) & 3, e = b & 7;
            #pragma unroll
            for (int s = 0; s < S_; s++)
                Vf[((size_t)(j * KBT + kb) * 64 + (s | (lh << 4))) * 8 + e] =
                    f2bf(sv[s] * scale);
        } else {
            float o16[S_];
            #pragma unroll
            for (int s = 0; s < S_; s++) o16[s] = sv[s] * scale;
            float* dst = &out[((size_t)b * J_ + j) * S_];
            #pragma unroll
            for (int r4 = 0; r4 < 4; r4++)
                *(float4*)(dst + r4 * 4) = *(float4*)(o16 + r4 * 4);
        }
    }
}

// ---------------------------------------------------------------------------
// TGEMM + fused b_ij update, LDS-free; ILP-2 MFMA accumulators.
// grid(72 ntg, 10 j), 512 threads.
__global__ __launch_bounds__(512) void k_tgemm_bup(const short8* __restrict__ Vf,
                                                   const short8* __restrict__ Bt,
                                                   const unsigned short* __restrict__ W2,
                                                   float* __restrict__ b_ij) {
    const int t = threadIdx.x, w = t >> 6, L = t & 63;
    const int j = blockIdx.y, ntg = blockIdx.x;
    const int nt = ntg * 8 + w;
    const short8* pA = Vf + (size_t)j * KBT * 64 + L;
    const short8* pB = Bt + (size_t)nt * KBT * 64 + L;
    floatx4 a0 = {0.f, 0.f, 0.f, 0.f}, a1 = a0;
    #pragma unroll
    for (int kb = 0; kb < KBT; kb += 2) {
        a0 = __builtin_amdgcn_mfma_f32_16x16x32_bf16(pA[kb * 64], pB[kb * 64], a0, 0, 0, 0);
        a1 = __builtin_amdgcn_mfma_f32_16x16x32_bf16(pA[(kb + 1) * 64], pB[(kb + 1) * 64], a1, 0, 0, 0);
    }
    floatx4 a = a0 + a1;
    const int col = L & 15, rw = (L >> 4) << 2;
    const int i = nt / 72;
    const int c = (nt % 72) * 16 + col;
    const unsigned short* wp = W2 + ((size_t)(j * 8 + i) * C_ + c) * 16 + rw;
    uint2 wv = *(const uint2*)wp;
    float p = a[0] * __uint_as_float((unsigned int)wv.x << 16)
            + a[1] * __uint_as_float(wv.x & 0xffff0000u)
            + a[2] * __uint_as_float((unsigned int)wv.y << 16)
            + a[3] * __uint_as_float(wv.y & 0xffff0000u);
    p += __shfl_xor(p, 16);
    p += __shfl_xor(p, 32);
    if ((L >> 4) == 0)
        atomicAdd(&b_ij[c * J_ + j], p * (1.0f / 512.f));
}

// ---------------------------------------------------------------------------
extern "C" void kernel_launch(void* const* d_in, const int* in_sizes, int n_in,
                              void* d_out, int out_size, void* d_ws, size_t ws_size,
                              hipStream_t stream) {
    const float* x = (const float*)d_in[0];   // [512][8][1152]
    const float* W = (const float*)d_in[1];   // [1152][10][16][8]
    float* out = (float*)d_out;               // [512][10][16][1]
    float* ws  = (float*)d_ws;

    float* Bs_f = ws;                    // 2,359,296
    float* Bt_f = Bs_f + 2359296;        // 2,359,296
    float* Wf_f = Bt_f + 2359296;        //   737,280
    float* W2_f = Wf_f + 737280;         //   737,280
    float* Vf_f = W2_f + 737280;         //    40,960
    float* bij  = Vf_f + 40960;          //    11,520
    // total ~25 MB

    k_pack<<<721, 512, 0, stream>>>(x, W, (uint4*)Bs_f, (uint4*)Bt_f,
                                    (uint4*)Wf_f, (unsigned short*)W2_f, bij);

    k_sgemm_f<<<dim3(32, 10), 512, 0, stream>>>(
        (const short8*)Wf_f, (const short8*)Bs_f, bij,
        (unsigned short*)Vf_f, out, 0);
    k_tgemm_bup<<<dim3(72, 10), 512, 0, stream>>>(
        (const short8*)Vf_f, (const short8*)Bt_f, (const unsigned short*)W2_f, bij);

    k_sgemm_f<<<dim3(32, 10), 512, 0, stream>>>(
        (const short8*)Wf_f, (const short8*)Bs_f, bij,
        (unsigned short*)Vf_f, out, 1);
    k_tgemm_bup<<<dim3(72, 10), 512, 0, stream>>>(
        (const short8*)Vf_f, (const short8*)Bt_f, (const unsigned short*)W2_f, bij);

    k_sgemm_f<<<dim3(32, 10), 512, 0, stream>>>(
        (const short8*)Wf_f, (const short8*)Bs_f, bij,
        (unsigned short*)Vf_f, out, 2);
}

// Round 14
// 134.237 us; speedup vs baseline: 1.0073x; 1.0073x over previous
//
#include <hip/hip_runtime.h>
#include <hip/hip_bf16.h>
#include <math.h>

#define B_  512
#define I_  8
#define C_  1152
#define J_  10
#define S_  16
#define K1  9216
#define NKB 288     // sgemm K-blocks (K=9216/32)
#define KBT 16      // tgemm K-blocks (K=512/32)

typedef short short8 __attribute__((ext_vector_type(8)));
typedef float floatx4 __attribute__((ext_vector_type(4)));

__device__ inline unsigned short f2bf(float f) {
    unsigned int u = __float_as_uint(f);
    return (unsigned short)((u + 0x7FFFu + ((u >> 16) & 1u)) >> 16);
}
// HW packed f32->bf16 RNE (v_cvt_pk_bf16_f32 on gfx950): low16 = a, high16 = b
__device__ inline unsigned int pack2(float a, float b) {
    __hip_bfloat162 h = __float22bfloat162_rn(float2{a, b});
    return *reinterpret_cast<unsigned int*>(&h);
}

// ---------------------------------------------------------------------------
// PACK: 721 blocks x 512 threads (reads x once; zeroes b_ij).
__global__ __launch_bounds__(512) void k_pack(const float* __restrict__ x,
                                              const float* __restrict__ W,
                                              uint4* __restrict__ Bs,
                                              uint4* __restrict__ Bt,
                                              uint4* __restrict__ Wf,
                                              unsigned short* __restrict__ W2,
                                              float* __restrict__ b_ij) {
    __shared__ float lds[10240];
    const int task = blockIdx.x;
    const int t = threadIdx.x;
    const int w = t >> 6, L = t & 63, quad = L >> 4;

    if (task < 576) {                       // ---- x tile -> Bs + Bt
        const int bt = task / 36, kt = task % 36;
        const int b0 = bt * 32, k0 = kt * 256;
        #pragma unroll
        for (int p = 0; p < 4; p++) {
            int f4 = p * 512 + t;
            int row = f4 >> 6, c4 = (f4 & 63) << 2;
            *(float4*)&lds[row * 260 + c4] =
                *(const float4*)&x[(size_t)(b0 + row) * K1 + k0 + c4];
        }
        __syncthreads();
        #pragma unroll
        for (int p = 0; p < 2; p++) {
            const int bl = p * 16 + (L & 15);
            const float* s = &lds[bl * 260 + w * 32 + quad * 8];
            uint4 o;
            o.x = pack2(s[0], s[1]); o.y = pack2(s[2], s[3]);
            o.z = pack2(s[4], s[5]); o.w = pack2(s[6], s[7]);
            Bs[((size_t)(bt * 2 + p) * NKB + kt * 8 + w) * 64 + L] = o;
        }
        #pragma unroll
        for (int p = 0; p < 2; p++) {
            const int ntl = w * 2 + p;
            const int nl = ntl * 16 + (L & 15);
            float v[8];
            #pragma unroll
            for (int e = 0; e < 8; e++) v[e] = lds[(quad * 8 + e) * 260 + nl];
            uint4 o;
            o.x = pack2(v[0], v[1]); o.y = pack2(v[2], v[3]);
            o.z = pack2(v[4], v[5]); o.w = pack2(v[6], v[7]);
            Bt[((size_t)(kt * 16 + ntl) * KBT + bt) * 64 + L] = o;
        }
    } else if (task < 720) {                // ---- W chunk -> Wf + W2
        const int c0 = (task - 576) * 8;
        #pragma unroll
        for (int p = 0; p < 5; p++) {
            int f4 = p * 512 + t;
            int cc = f4 / 320, off4 = (f4 % 320) << 2;
            *(float4*)&lds[cc * 1280 + off4] =
                *(const float4*)&W[(size_t)(c0 + cc) * 1280 + off4];
        }
        __syncthreads();
        #pragma unroll
        for (int p = 0; p < 3; p++) {
            int o = p * 512 + t;
            if (o < 1280) {
                int j = o >> 7, i = (o >> 4) & 7, m = o & 15;
                int k0w = i * C_ + c0;
                int Lw = m | (((k0w >> 3) & 3) << 4);
                float v[8];
                #pragma unroll
                for (int e = 0; e < 8; e++)
                    v[e] = lds[e * 1280 + j * 128 + m * 8 + i];
                uint4 og;
                og.x = pack2(v[0], v[1]); og.y = pack2(v[2], v[3]);
                og.z = pack2(v[4], v[5]); og.w = pack2(v[6], v[7]);
                Wf[((size_t)j * NKB + (k0w >> 5)) * 64 + Lw] = og;
            }
        }
        #pragma unroll
        for (int p = 0; p < 2; p++) {
            int o = p * 512 + t;
            if (o < 640) {
                int j = o >> 6, i = (o >> 3) & 7, cc = o & 7;
                unsigned int r8[8];
                #pragma unroll
                for (int h = 0; h < 8; h++)
                    r8[h] = pack2(lds[cc * 1280 + j * 128 + (2 * h) * 8 + i],
                                  lds[cc * 1280 + j * 128 + (2 * h + 1) * 8 + i]);
                unsigned short* dst = W2 + ((size_t)(j * 8 + i) * C_ + c0 + cc) * 16;
                *(uint4*)dst       = make_uint4(r8[0], r8[1], r8[2], r8[3]);
                *(uint4*)(dst + 8) = make_uint4(r8[4], r8[5], r8[6], r8[7]);
            }
        }
    } else {                                // ---- zero b_ij
        for (int idx = t; idx < C_ * J_; idx += 512) b_ij[idx] = 0.0f;
    }
}

// ---------------------------------------------------------------------------
// SGEMM + fused fold + reduce + squash.
// grid (32 nt, 10 j) = 320 blocks x 512 thr (8 waves = 8-way K-split).
// Fold uses HW v_cvt_pk_bf16_f32 via pack2 with full RNE (masked hi unpack).
// mode 0: uniform cnorm=0.1; mode 1: softmax fold -> Vf; mode 2: fold -> out.
__global__ __launch_bounds__(512) void k_sgemm_f(const short8* __restrict__ Wf,
                                                 const short8* __restrict__ Bs,
                                                 const float* __restrict__ b_ij,
                                                 unsigned short* __restrict__ Vf,
                                                 float* __restrict__ out,
                                                 int mode) {
    __shared__ float smf[1152 + 2048];   // cn[1152] + parts[8 waves][256]
    const int t = threadIdx.x, w = t >> 6, L = t & 63, quad = L >> 4;
    const int j  = blockIdx.y;
    const int nt = blockIdx.x;           // 16-b tile, 0..31

    if (mode) {
        for (int c = t; c < C_; c += 512) {
            float bv[J_], mx = -1e30f;
            #pragma unroll
            for (int jj = 0; jj < J_; jj++) {
                bv[jj] = b_ij[c * J_ + jj]; mx = fmaxf(mx, bv[jj]);
            }
            float sum = 0.0f;
            #pragma unroll
            for (int jj = 0; jj < J_; jj++) sum += __expf(bv[jj] - mx);
            smf[c] = __expf(bv[j] - mx) / sum;
        }
    }
    __syncthreads();

    const short8* pA = Wf + ((size_t)j * NKB + w * 36) * 64 + L;
    const short8* pB = Bs + ((size_t)nt * NKB + w * 36) * 64 + L;
    floatx4 acc = {0.f, 0.f, 0.f, 0.f};
    if (mode) {
        #pragma unroll 6
        for (int i = 0; i < 36; i++) {
            short8 a = pA[i * 64];
            const int cb = i * 32 + quad * 8;     // (w*36*32) % 1152 == 0
            float4 cl = *(const float4*)&smf[cb];
            float4 ch = *(const float4*)&smf[cb + 4];
            float cn8[8] = {cl.x, cl.y, cl.z, cl.w, ch.x, ch.y, ch.z, ch.w};
            unsigned int* au = (unsigned int*)&a;
            short8 a2; unsigned int* ao = (unsigned int*)&a2;
            #pragma unroll
            for (int h = 0; h < 4; h++) {
                float f0 = __uint_as_float(au[h] << 16)         * cn8[2 * h];
                float f1 = __uint_as_float(au[h] & 0xffff0000u) * cn8[2 * h + 1];
                ao[h] = pack2(f0, f1);
            }
            acc = __builtin_amdgcn_mfma_f32_16x16x32_bf16(a2, pB[i * 64], acc, 0, 0, 0);
        }
    } else {
        #pragma unroll 6
        for (int i = 0; i < 36; i++)
            acc = __builtin_amdgcn_mfma_f32_16x16x32_bf16(pA[i * 64], pB[i * 64], acc, 0, 0, 0);
    }

    const int col = L & 15, rw = quad << 2;
    float* base = &smf[1152 + w * 256];
    #pragma unroll
    for (int r = 0; r < 4; r++)
        base[(rw + r) * 16 + col] = acc[r];
    __syncthreads();

    if (t < 16) {                        // reduce 8 partials + squash (bl = t)
        float sv[S_]; float msq = 0.f;
        #pragma unroll
        for (int s = 0; s < S_; s++) {
            float a = 0.f;
            #pragma unroll
            for (int w8 = 0; w8 < 8; w8++)
                a += smf[1152 + w8 * 256 + s * 16 + t];
            if (mode == 0) a *= 0.1f;
            sv[s] = a; msq += a * a;
        }
        const float scale = msq / ((1.f + msq) * sqrtf(msq));
        const int b = nt * 16 + t;       // global b (0..511)
        if (mode < 2) {
            const int kb = b >> 5, lh = (b >> 3) & 3, e = b & 7;
            #pragma unroll
            for (int s = 0; s < S_; s++)
                Vf[((size_t)(j * KBT + kb) * 64 + (s | (lh << 4))) * 8 + e] =
                    f2bf(sv[s] * scale);
        } else {
            float o16[S_];
            #pragma unroll
            for (int s = 0; s < S_; s++) o16[s] = sv[s] * scale;
            float* dst = &out[((size_t)b * J_ + j) * S_];
            #pragma unroll
            for (int r4 = 0; r4 < 4; r4++)
                *(float4*)(dst + r4 * 4) = *(float4*)(o16 + r4 * 4);
        }
    }
}

// ---------------------------------------------------------------------------
// TGEMM + fused b_ij update, LDS-free (in-register W2 contraction +
// cross-quad shfl reduce). grid(72 ntg, 10 j), 512 threads.
__global__ __launch_bounds__(512) void k_tgemm_bup(const short8* __restrict__ Vf,
                                                   const short8* __restrict__ Bt,
                                                   const unsigned short* __restrict__ W2,
                                                   float* __restrict__ b_ij) {
    const int t = threadIdx.x, w = t >> 6, L = t & 63;
    const int j = blockIdx.y, ntg = blockIdx.x;
    const int nt = ntg * 8 + w;
    const short8* pA = Vf + (size_t)j * KBT * 64 + L;
    const short8* pB = Bt + (size_t)nt * KBT * 64 + L;
    floatx4 a = {0.f, 0.f, 0.f, 0.f};
    #pragma unroll
    for (int kb = 0; kb < KBT; kb++)
        a = __builtin_amdgcn_mfma_f32_16x16x32_bf16(pA[kb * 64], pB[kb * 64], a, 0, 0, 0);
    const int col = L & 15, rw = (L >> 4) << 2;
    const int i = nt / 72;
    const int c = (nt % 72) * 16 + col;
    const unsigned short* wp = W2 + ((size_t)(j * 8 + i) * C_ + c) * 16 + rw;
    uint2 wv = *(const uint2*)wp;
    float p = a[0] * __uint_as_float((unsigned int)wv.x << 16)
            + a[1] * __uint_as_float(wv.x & 0xffff0000u)
            + a[2] * __uint_as_float((unsigned int)wv.y << 16)
            + a[3] * __uint_as_float(wv.y & 0xffff0000u);
    p += __shfl_xor(p, 16);
    p += __shfl_xor(p, 32);
    if ((L >> 4) == 0)
        atomicAdd(&b_ij[c * J_ + j], p * (1.0f / 512.f));
}

// ---------------------------------------------------------------------------
extern "C" void kernel_launch(void* const* d_in, const int* in_sizes, int n_in,
                              void* d_out, int out_size, void* d_ws, size_t ws_size,
                              hipStream_t stream) {
    const float* x = (const float*)d_in[0];   // [512][8][1152]
    const float* W = (const float*)d_in[1];   // [1152][10][16][8]
    float* out = (float*)d_out;               // [512][10][16][1]
    float* ws  = (float*)d_ws;

    float* Bs_f = ws;                    // 2,359,296
    float* Bt_f = Bs_f + 2359296;        // 2,359,296
    float* Wf_f = Bt_f + 2359296;        //   737,280
    float* W2_f = Wf_f + 737280;         //   737,280
    float* Vf_f = W2_f + 737280;         //    40,960
    float* bij  = Vf_f + 40960;          //    11,520
    // total ~25 MB

    k_pack<<<721, 512, 0, stream>>>(x, W, (uint4*)Bs_f, (uint4*)Bt_f,
                                    (uint4*)Wf_f, (unsigned short*)W2_f, bij);

    k_sgemm_f<<<dim3(32, 10), 512, 0, stream>>>(
        (const short8*)Wf_f, (const short8*)Bs_f, bij,
        (unsigned short*)Vf_f, out, 0);
    k_tgemm_bup<<<dim3(72, 10), 512, 0, stream>>>(
        (const short8*)Vf_f, (const short8*)Bt_f, (const unsigned short*)W2_f, bij);

    k_sgemm_f<<<dim3(32, 10), 512, 0, stream>>>(
        (const short8*)Wf_f, (const short8*)Bs_f, bij,
        (unsigned short*)Vf_f, out, 1);
    k_tgemm_bup<<<dim3(72, 10), 512, 0, stream>>>(
        (const short8*)Vf_f, (const short8*)Bt_f, (const unsigned short*)W2_f, bij);

    k_sgemm_f<<<dim3(32, 10), 512, 0, stream>>>(
        (const short8*)Wf_f, (const short8*)Bs_f, bij,
        (unsigned short*)Vf_f, out, 2);
}